// Round 5
// baseline (126.990 us; speedup 1.0000x reference)
//
#include <hip/hip_runtime.h>

// Problem constants (fixed by the reference file).
#define DIN  4096
#define NG   4096          // NUM_GATES = DOUT/3
#define BS   4096
#define RPB  8             // rows per block -> 512 blocks = 2 blocks/CU, 32 waves/CU
#define BT   1024          // 16 waves; block covers ALL 4096 gates (4 per thread)
#define WROW 4112          // 4096 floats + 16 pad (wrap tail, keeps 16B alignment)

typedef float v4f __attribute__((ext_vector_type(4)));

// out[b,g] = w0*x[b,(3g+1)&4095] + w1*x[b,(3g+2)&4095] + w2*x[b,(3g+3)&4095] + w3
// (w0..w3) = softmax(wgts[g,0,0..3]). Reference's signals[:, :, ::3] selects only
// row 0 of M = [1,0,0,0,0] -> out = s[...,0]; v4/v5 and rows 1..2 are dead code.
//
// R5: 2 rows per barrier (half the barrier count of R4), prefetch depth = 2 rows
// (32 KB/block in flight ACROSS the barrier — register staging, not
// global_load_lds, precisely so the barrier's waitcnt doesn't drain them).
// Tail element read as a 4th ds_read_b128 (16-lane phases -> 2-way -> free)
// instead of ds_read_b32 at stride 12 (8-way conflict).
__global__ __launch_bounds__(BT) void fredkin_s0_p2(
    const float* __restrict__ x,
    const float* __restrict__ wgts,
    float* __restrict__ out)
{
    __shared__ float xs[4][WROW];   // two double-buffered row-pairs

    const int tid = threadIdx.x;
    const int g0  = 4 * tid;

    // Softmax of wgts[g,0,:] for this thread's 4 gates (row-0 at float offset 12g,
    // 16B aligned). Once per block, amortized over RPB rows; wgts is L2-resident.
    float4 w[4];
#pragma unroll
    for (int j = 0; j < 4; ++j) {
        float4 r = *reinterpret_cast<const float4*>(wgts + (size_t)(g0 + j) * 12);
        float m  = fmaxf(fmaxf(r.x, r.y), fmaxf(r.z, r.w));
        float e0 = __expf(r.x - m);
        float e1 = __expf(r.y - m);
        float e2 = __expf(r.z - m);
        float e3 = __expf(r.w - m);
        float inv = 1.0f / (e0 + e1 + e2 + e3);
        w[j] = make_float4(e0 * inv, e1 * inv, e2 * inv, e3 * inv);
    }

    const int lb = (12 * tid) & (DIN - 1);   // window start in LDS (uses lb+1..lb+12)

    const int brow = blockIdx.x * RPB;
    const float* xr   = x   + (size_t)brow * DIN + 4 * tid;   // this thread's float4
    float*       orow = out + (size_t)brow * NG + g0;

    // Prefetch rows 0 and 1 (nontemporal: each row is consumed exactly once).
    v4f v0 = __builtin_nontemporal_load(reinterpret_cast<const v4f*>(xr));
    v4f v1 = __builtin_nontemporal_load(reinterpret_cast<const v4f*>(xr + DIN));

    for (int r = 0; r < RPB; r += 2) {
        float* b0 = xs[(r & 2) ? 2 : 0];
        float* b1 = xs[(r & 2) ? 3 : 1];
        *reinterpret_cast<v4f*>(&b0[4 * tid]) = v0;
        *reinterpret_cast<v4f*>(&b1[4 * tid]) = v1;
        if (tid < 4) {                                  // replicate floats 0..15 as pad
            *reinterpret_cast<v4f*>(&b0[DIN + 4 * tid]) = v0;
            *reinterpret_cast<v4f*>(&b1[DIN + 4 * tid]) = v1;
        }

        if (r + 2 < RPB) {                              // prefetch next pair; stays in
            v0 = __builtin_nontemporal_load(reinterpret_cast<const v4f*>(xr + 2 * DIN));
            v1 = __builtin_nontemporal_load(reinterpret_cast<const v4f*>(xr + 3 * DIN));
        }

        __syncthreads();   // only barrier per 2 rows; other buffer pair next iter

#pragma unroll
        for (int q = 0; q < 2; ++q) {
            const float* buf = q ? b1 : b0;
            float4 f0 = *reinterpret_cast<const float4*>(&buf[lb]);       // e0..e3
            float4 f1 = *reinterpret_cast<const float4*>(&buf[lb + 4]);   // e4..e7
            float4 f2 = *reinterpret_cast<const float4*>(&buf[lb + 8]);   // e8..e11
            float4 f3 = *reinterpret_cast<const float4*>(&buf[lb + 12]);  // e12 in .x

            v4f o;
            o.x = fmaf(w[0].x, f0.y, fmaf(w[0].y, f0.z, fmaf(w[0].z, f0.w, w[0].w)));
            o.y = fmaf(w[1].x, f1.x, fmaf(w[1].y, f1.y, fmaf(w[1].z, f1.z, w[1].w)));
            o.z = fmaf(w[2].x, f1.w, fmaf(w[2].y, f2.x, fmaf(w[2].z, f2.y, w[2].w)));
            o.w = fmaf(w[3].x, f2.z, fmaf(w[3].y, f2.w, fmaf(w[3].z, f3.x, w[3].w)));

            __builtin_nontemporal_store(o, reinterpret_cast<v4f*>(orow + q * NG));
        }

        xr   += 2 * DIN;
        orow += 2 * NG;
    }
}

extern "C" void kernel_launch(void* const* d_in, const int* in_sizes, int n_in,
                              void* d_out, int out_size, void* d_ws, size_t ws_size,
                              hipStream_t stream) {
    const float* x    = (const float*)d_in[0];   // (BS, DIN) fp32
    const float* wgts = (const float*)d_in[1];   // (NG, 3, 4) fp32
    // d_in[2] (connections) is deterministic: (3g+1+j) % DIN — computed inline.
    float* out = (float*)d_out;                  // (BS, NG) fp32

    fredkin_s0_p2<<<dim3(BS / RPB), dim3(BT), 0, stream>>>(x, wgts, out);
}

// Round 7
// 125.071 us; speedup vs baseline: 1.0153x; 1.0153x over previous
//
#include <hip/hip_runtime.h>

// Problem constants (fixed by the reference file).
#define DIN  4096
#define NG   4096          // NUM_GATES = DOUT/3
#define BS   4096
#define RPB  8             // rows per block -> 512 blocks = 2 blocks/CU, 32 waves/CU
#define BT   1024          // 16 waves; block covers ALL 4096 gates
#define WSL  768           // per-wave LDS slice (floats); reads max buf[767]

typedef float v4f __attribute__((ext_vector_type(4)));

// out[b,g] = w0*x[b,(3g+1)&4095] + w1*x[b,(3g+2)&4095] + w2*x[b,(3g+3)&4095] + w3
// (w0..w3) = softmax(wgts[g,0,0..3]). Reference's signals[:, :, ::3] selects only
// row 0 of M = [1,0,0,0,0] -> out = s[...,0]; v4/v5 and rows 1..2 are dead code.
//
// R7: zero __syncthreads (no vmcnt(0) drain -> prefetch lives across iterations),
// wave-private LDS staging. R6's race is fixed:
//  - __builtin_amdgcn_wave_barrier() fences compiler code motion around the
//    intra-wave LDS write->read handoff (HW side is safe: waves issue in order
//    and the DS pipe processes a wave's ops in order).
//  - The window tail e12 no longer goes through LDS at all: lane l gets it as
//    lane l+1's f0.x via __shfl_down; lane 63 uses a wave-uniform scalar load.
__global__ __launch_bounds__(BT, 8) void fredkin_s0_wsync(
    const float* __restrict__ x,
    const float* __restrict__ wgts,
    float* __restrict__ out)
{
    __shared__ float xs[16 * WSL];

    const int tid = threadIdx.x;
    const int w   = tid >> 6;        // wave 0..15
    const int l   = tid & 63;        // lane
    float* buf = &xs[w * WSL];       // wave-private slice

    const int g0 = 256 * w + 4 * l;  // first of this thread's 4 gates

    // Softmax of wgts[g,0,:] (row-0 at float offset 12g, 16B aligned). Once per
    // block, amortized over RPB rows; wgts (192KB) is L2-resident.
    float4 wq[4];
#pragma unroll
    for (int j = 0; j < 4; ++j) {
        float4 r = *reinterpret_cast<const float4*>(wgts + (size_t)(g0 + j) * 12);
        float m  = fmaxf(fmaxf(r.x, r.y), fmaxf(r.z, r.w));
        float e0 = __expf(r.x - m);
        float e1 = __expf(r.y - m);
        float e2 = __expf(r.z - m);
        float e3 = __expf(r.w - m);
        float inv = 1.0f / (e0 + e1 + e2 + e3);
        wq[j] = make_float4(e0 * inv, e1 * inv, e2 * inv, e3 * inv);
    }

    // Wave window: row floats [768w, 768w+768] (mod DIN); base mult of 4 so the
    // &4095 wrap never splits an aligned float4.
    const int wb = (768 * w) & (DIN - 1);
    const int o0 = (wb + 4 * l)       & (DIN - 1);
    const int o1 = (wb + 4 * l + 256) & (DIN - 1);
    const int o2 = (wb + 4 * l + 512) & (DIN - 1);
    const int ot = (wb + 768)         & (DIN - 1);   // wave-uniform tail float

    const int brow = blockIdx.x * RPB;
    const float* xr   = x   + (size_t)brow * DIN;
    float*       orow = out + (size_t)brow * NG + g0;

    // Prefetch row 0 (plain loads: the 3x logical reuse wants L2 caching).
    v4f a0 = *reinterpret_cast<const v4f*>(xr + o0);
    v4f a1 = *reinterpret_cast<const v4f*>(xr + o1);
    v4f a2 = *reinterpret_cast<const v4f*>(xr + o2);
    float at = xr[ot];               // broadcast (lane-uniform address)

    const int lb = 12 * l;           // this thread's window start in the slice

    for (int r = 0; r < RPB; ++r) {
        // Stage row r (b128 writes, 16B lane stride = 2-way bank alias = free).
        *reinterpret_cast<v4f*>(&buf[4 * l])       = a0;
        *reinterpret_cast<v4f*>(&buf[4 * l + 256]) = a1;
        *reinterpret_cast<v4f*>(&buf[4 * l + 512]) = a2;

        const float tail = at;       // row r's tail, held in-register

        // Prefetch row r+1 — no barrier anywhere will drain these.
        if (r + 1 < RPB) {
            const float* xn = xr + DIN;
            a0 = *reinterpret_cast<const v4f*>(xn + o0);
            a1 = *reinterpret_cast<const v4f*>(xn + o1);
            a2 = *reinterpret_cast<const v4f*>(xn + o2);
            at = xn[ot];
        }

        __builtin_amdgcn_wave_barrier();   // stage(r) stays above reads(r)

        // ds_read_b128 at 48B lane stride: 2-way bank aliasing per phase = free.
        float4 f0 = *reinterpret_cast<const float4*>(&buf[lb]);      // e0..e3
        float4 f1 = *reinterpret_cast<const float4*>(&buf[lb + 4]);  // e4..e7
        float4 f2 = *reinterpret_cast<const float4*>(&buf[lb + 8]);  // e8..e11

        // e12 = buf[12l+12] = lane (l+1)'s f0.x; lane 63 uses the uniform tail.
        float e12 = __shfl_down(f0.x, 1);
        if (l == 63) e12 = tail;

        v4f o;
        o.x = fmaf(wq[0].x, f0.y, fmaf(wq[0].y, f0.z, fmaf(wq[0].z, f0.w, wq[0].w)));
        o.y = fmaf(wq[1].x, f1.x, fmaf(wq[1].y, f1.y, fmaf(wq[1].z, f1.z, wq[1].w)));
        o.z = fmaf(wq[2].x, f1.w, fmaf(wq[2].y, f2.x, fmaf(wq[2].z, f2.y, wq[2].w)));
        o.w = fmaf(wq[3].x, f2.z, fmaf(wq[3].y, f2.w, fmaf(wq[3].z, e12, wq[3].w)));

        __builtin_nontemporal_store(o, reinterpret_cast<v4f*>(orow));

        __builtin_amdgcn_wave_barrier();   // reads(r) stay above stage(r+1)

        xr   += DIN;
        orow += NG;
    }
}

extern "C" void kernel_launch(void* const* d_in, const int* in_sizes, int n_in,
                              void* d_out, int out_size, void* d_ws, size_t ws_size,
                              hipStream_t stream) {
    const float* x    = (const float*)d_in[0];   // (BS, DIN) fp32
    const float* wgts = (const float*)d_in[1];   // (NG, 3, 4) fp32
    // d_in[2] (connections) is deterministic: (3g+1+j) % DIN — computed inline.
    float* out = (float*)d_out;                  // (BS, NG) fp32

    fredkin_s0_wsync<<<dim3(BS / RPB), dim3(BT), 0, stream>>>(x, wgts, out);
}

// Round 8
// 116.322 us; speedup vs baseline: 1.0917x; 1.0752x over previous
//
#include <hip/hip_runtime.h>

// Problem constants (fixed by the reference file).
#define DIN 4096
#define NG  4096           // NUM_GATES = DOUT/3
#define BS  4096
#define RPB 8              // rows per block -> 512 blocks = 2 blocks/CU, 32 waves/CU
#define BT  1024           // 16 waves; block covers ALL 4096 gates (4 per thread)

typedef float v4f __attribute__((ext_vector_type(4)));

// Wait until at most N vector-memory ops outstanding; leave lgkm/exp unconstrained.
#define WAITVM(N) __builtin_amdgcn_s_waitcnt((N) | 0x0F70)

// Async global->LDS DMA, 16B per lane. LDS dest = wave-uniform base + lane*16.
__device__ __forceinline__ void dma16(const float* g, float* lds) {
    __builtin_amdgcn_global_load_lds(
        (const __attribute__((address_space(1))) void*)g,
        (__attribute__((address_space(3))) void*)lds, 16, 0, 0);
}

// out[b,g] = w0*x[b,(3g+1)&4095] + w1*x[b,(3g+2)&4095] + w2*x[b,(3g+3)&4095] + w3
// (w0..w3) = softmax(wgts[g,0,0..3]). Reference's signals[:, :, ::3] selects only
// row 0 of M = [1,0,0,0,0] -> out = s[...,0]; v4/v5 and rows 1..2 are dead code.
//
// R8: global_load_lds staging into 4 LDS row-buffers, 3 rows in flight, raw
// s_barrier + exact s_waitcnt vmcnt(N) per unrolled iter (prefetch survives the
// barrier — the thing __syncthreads' vmcnt(0) drain forbids). No ds_writes, no
// VGPR round-trip. Correctness: each wave drains ITS DMA(r) via WAITVM(N) BEFORE
// s_barrier => after the barrier all 16 waves' row-r chunks are in LDS. A buffer
// DMA'd at iter r was last read at iter r-1; those reads were consumed (lgkm
// drained before the FMAs) before any wave passed barrier(r) => no WAW race.
__global__ __launch_bounds__(BT, 8) void fredkin_s0_dma(
    const float* __restrict__ x,
    const float* __restrict__ wgts,
    float* __restrict__ out)
{
    // 4 SEPARATE objects so LLVM's per-object LDS-DMA tracking doesn't
    // conservatively drain all outstanding DMAs before each ds_read.
    __shared__ float B0[DIN], B1[DIN], B2[DIN], B3[DIN];

    const int tid = threadIdx.x;
    const int w   = tid >> 6;        // wave 0..15
    const int l   = tid & 63;        // lane
    const int g0  = 4 * tid;         // first of this thread's 4 gates

    // Softmax of wgts[g,0,:] (row-0 at float offset 12g, 16B aligned). Once per
    // block; these loads are consumed (exp/div) before the DMAs are issued, so
    // they don't perturb the manual vmcnt bookkeeping below.
    float4 wq[4];
#pragma unroll
    for (int j = 0; j < 4; ++j) {
        float4 r = *reinterpret_cast<const float4*>(wgts + (size_t)(g0 + j) * 12);
        float m  = fmaxf(fmaxf(r.x, r.y), fmaxf(r.z, r.w));
        float e0 = __expf(r.x - m);
        float e1 = __expf(r.y - m);
        float e2 = __expf(r.z - m);
        float e3 = __expf(r.w - m);
        float inv = 1.0f / (e0 + e1 + e2 + e3);
        wq[j] = make_float4(e0 * inv, e1 * inv, e2 * inv, e3 * inv);
    }

    const int brow = blockIdx.x * RPB;
    const float* xb   = x   + (size_t)brow * DIN;    // block's row 0
    float*       orow = out + (size_t)brow * NG + g0;
    const int doff = 256 * w + 4 * l;                // lane's chunk offset (floats)

    // Window reads: per-float4 &4095 handles the 3 wrapping threads per block.
    const int lb = (12 * tid) & (DIN - 1);
    const int i1 = (lb + 4)  & (DIN - 1);
    const int i2 = (lb + 8)  & (DIN - 1);
    const int i3 = (lb + 12) & (DIN - 1);

    // Prologue: rows 0..2 in flight (1 DMA instr per wave per row).
    dma16(xb + 0 * DIN + doff, B0 + 256 * w);
    dma16(xb + 1 * DIN + doff, B1 + 256 * w);
    dma16(xb + 2 * DIN + doff, B2 + 256 * w);

    // Per-iter vmem issue order: [WAITVM; s_barrier; DMA(r+3); reads; store(r)].
    // NWAIT = #vmem ops newer than DMA(r) at the wait point (exact FIFO count):
    // r: 0:2 (D1,D2) 1:3 (D2,D3,s0) 2:4 3:5 4:5 5:5 6:4 7:3.
#define FRED_ITER(R, NWAIT, RBUF, WBUF, DO_DMA)                                     \
    {                                                                               \
        asm volatile("" ::: "memory");                                              \
        WAITVM(NWAIT);              /* own DMA(R) retired */                        \
        __builtin_amdgcn_s_barrier(); /* => ALL waves' DMA(R) retired */            \
        asm volatile("" ::: "memory");                                              \
        if (DO_DMA) dma16(xb + (size_t)(R + 3) * DIN + doff, WBUF + 256 * w);       \
        float4 f0 = *reinterpret_cast<const float4*>(&RBUF[lb]);   /* e0..e3  */    \
        float4 f1 = *reinterpret_cast<const float4*>(&RBUF[i1]);   /* e4..e7  */    \
        float4 f2 = *reinterpret_cast<const float4*>(&RBUF[i2]);   /* e8..e11 */    \
        float e12 = __shfl_down(f0.x, 1);       /* e12 = next thread's f0.x */      \
        if (l == 63) e12 = RBUF[i3];            /* cross-wave seam: 1-lane read */  \
        v4f o;                                                                      \
        o.x = fmaf(wq[0].x, f0.y, fmaf(wq[0].y, f0.z, fmaf(wq[0].z, f0.w, wq[0].w))); \
        o.y = fmaf(wq[1].x, f1.x, fmaf(wq[1].y, f1.y, fmaf(wq[1].z, f1.z, wq[1].w))); \
        o.z = fmaf(wq[2].x, f1.w, fmaf(wq[2].y, f2.x, fmaf(wq[2].z, f2.y, wq[2].w))); \
        o.w = fmaf(wq[3].x, f2.z, fmaf(wq[3].y, f2.w, fmaf(wq[3].z, e12, wq[3].w))); \
        __builtin_nontemporal_store(o, reinterpret_cast<v4f*>(orow + (size_t)(R) * NG)); \
    }

    FRED_ITER(0, 2, B0, B3, 1)
    FRED_ITER(1, 3, B1, B0, 1)
    FRED_ITER(2, 4, B2, B1, 1)
    FRED_ITER(3, 5, B3, B2, 1)
    FRED_ITER(4, 5, B0, B3, 1)
    FRED_ITER(5, 5, B1, B0, 0)
    FRED_ITER(6, 4, B2, B1, 0)
    FRED_ITER(7, 3, B3, B2, 0)
#undef FRED_ITER
}

extern "C" void kernel_launch(void* const* d_in, const int* in_sizes, int n_in,
                              void* d_out, int out_size, void* d_ws, size_t ws_size,
                              hipStream_t stream) {
    const float* x    = (const float*)d_in[0];   // (BS, DIN) fp32
    const float* wgts = (const float*)d_in[1];   // (NG, 3, 4) fp32
    // d_in[2] (connections) is deterministic: (3g+1+j) % DIN — computed inline.
    float* out = (float*)d_out;                  // (BS, NG) fp32

    fredkin_s0_dma<<<dim3(BS / RPB), dim3(BT), 0, stream>>>(x, wgts, out);
}